// Round 2
// 359.943 us; speedup vs baseline: 1.3684x; 1.3684x over previous
//
#include <hip/hip_runtime.h>

#define CH    256
#define NTOK  2304
#define MATSZ (CH * NTOK)   // 589824 elements per (b, matrix)

typedef __bf16 bf16x8 __attribute__((ext_vector_type(8)));
typedef float  f4v    __attribute__((ext_vector_type(4)));
typedef unsigned int u32x4 __attribute__((ext_vector_type(4)));

__device__ __forceinline__ unsigned short f2bf(float f) {
    union { float f; unsigned int i; } c;
    c.f = f;
    unsigned int x = c.i;
    x += 0x7fffu + ((x >> 16) & 1u);   // round-to-nearest-even
    return (unsigned short)(x >> 16);
}

__device__ __forceinline__ bf16x8 cvt8(const float* p) {
    union { bf16x8 v; unsigned short s[8]; } u;
#pragma unroll
    for (int i = 0; i < 8; ++i) u.s[i] = f2bf(p[i]);
    return u.v;
}

// ---------------------------------------------------------------------------
// 64x64-tiled transpose + fp32->bf16: in (R x Ccols) row-major fp32 ->
// out (Ccols x R) bf16. blockIdx.y = s*8 + b (s: 0=left 1=right).
// (unchanged — HW-verified)
// ---------------------------------------------------------------------------
__global__ __launch_bounds__(256) void tpose_k(
    const float* __restrict__ inL,
    const float* __restrict__ inR,
    unsigned short* __restrict__ out, int R, int Ccols)
{
    __shared__ unsigned short tile[64][72];
    int mat = blockIdx.y;
    const float* in = (mat >= 8 ? inR : inL) + (size_t)(mat & 7) * MATSZ;
    unsigned short* o = out + (size_t)mat * MATSZ;
    int tC = Ccols >> 6;
    int r0 = (blockIdx.x / tC) << 6;
    int c0 = (blockIdx.x % tC) << 6;
    int t = threadIdx.x;
    int col = t & 63, rs = t >> 6;
#pragma unroll
    for (int i = 0; i < 16; ++i) {
        int row = rs + i * 4;
        tile[row][col] = f2bf(in[(size_t)(r0 + row) * Ccols + c0 + col]);
    }
    __syncthreads();
#pragma unroll
    for (int i = 0; i < 16; ++i) {
        int crow = rs + i * 4;
        o[(size_t)(c0 + crow) * R + r0 + col] = tile[col][crow];
    }
}

// ---------------------------------------------------------------------------
// Projection: Y[o][pos] = BN(conv1x1(X)), bf16, (o, pos) layout.
// blockIdx.y = p*8 + b; p: 0=q(left) 1=q(right) 2=k(left) 3=k(right).
// (unchanged — HW-verified correct in R5/R6.)
// ---------------------------------------------------------------------------
__global__ __launch_bounds__(256, 2) void proj_k(
    const unsigned short* __restrict__ XT,   // [2][8][2304][256] bf16
    const float* __restrict__ Wq_, const float* __restrict__ Wk_,
    const float* __restrict__ bq_, const float* __restrict__ bk_,
    const float* __restrict__ gq_, const float* __restrict__ gk_,
    const float* __restrict__ beq_, const float* __restrict__ bek_,
    const float* __restrict__ mq_, const float* __restrict__ mk_,
    const float* __restrict__ vq_, const float* __restrict__ vk_,
    unsigned short* __restrict__ Yout)       // [4][8][MATSZ] bf16
{
    __shared__ __align__(16) unsigned short Xs[64][264];
    int pb = blockIdx.y;
    int p = pb >> 3, b = pb & 7;
    int s = p & 1, br = p >> 1;
    const unsigned short* X = XT + (size_t)(s * 8 + b) * MATSZ;
    const float* W  = br ? Wk_ : Wq_;
    const float* bb = br ? bk_ : bq_;
    const float* gg = br ? gk_ : gq_;
    const float* be = br ? bek_ : beq_;
    const float* mm = br ? mk_ : mq_;
    const float* vv = br ? vk_ : vq_;
    unsigned short* Yo = Yout + (size_t)pb * MATSZ;

    int ot = blockIdx.x & 3, pt = blockIdx.x >> 2;
    int o0 = ot * 64, pos0 = pt * 64;
    int t = threadIdx.x;
    int w = t >> 6, lane = t & 63;
    int l15 = lane & 15, quad = lane >> 4;

    {   // stage XT tile: 64 pos-rows x 256 c
        int r = t >> 2, cq = (t & 3) << 6;
        const unsigned short* src = X + (size_t)(pos0 + r) * CH + cq;
        unsigned short* dst = &Xs[r][cq];
#pragma unroll
        for (int k = 0; k < 8; ++k)
            *(u32x4*)(dst + k * 8) = *(const u32x4*)(src + k * 8);
    }
    bf16x8 wf[8];
    {
        const float* wp = W + (size_t)(o0 + w * 16 + l15) * CH + quad * 8;
#pragma unroll
        for (int kc = 0; kc < 8; ++kc)
            wf[kc] = cvt8(wp + kc * 32);
    }
    __syncthreads();

    f4v zero4 = {0.f, 0.f, 0.f, 0.f};
    f4v acc[4] = {zero4, zero4, zero4, zero4};
#pragma unroll
    for (int kc = 0; kc < 8; ++kc) {
#pragma unroll
        for (int ct = 0; ct < 4; ++ct) {
            bf16x8 xb = *(const bf16x8*)(&Xs[ct * 16 + l15][kc * 32 + quad * 8]);
            acc[ct] = __builtin_amdgcn_mfma_f32_16x16x32_bf16(wf[kc], xb, acc[ct], 0, 0, 0);
        }
    }
#pragma unroll
    for (int r = 0; r < 4; ++r) {
        int o = o0 + w * 16 + quad * 4 + r;
        float scale = gg[o] * rsqrtf(vv[o] + 1e-5f);
        float shift = (bb[o] - mm[o]) * scale + be[o];
#pragma unroll
        for (int ct = 0; ct < 4; ++ct) {
            float val = acc[ct][r] * scale + shift;
            Yo[(size_t)o * NTOK + pos0 + ct * 16 + l15] = f2bf(val);
        }
    }
}

// ---------------------------------------------------------------------------
// Fused attention. R2 = R1 with the K staging-swizzle constant FIXED:
//   key&7 = (t>>5)&7  (R1 wrote ((t>>5)&1) — 6/8 of key rows mis-slotted).
// Design (from R1):
//  * K/V LDS tiles LINEAR (no pad) with XOR swizzle byte^=((row&7)<<4) on
//    BOTH staging-write and fragment-read sides; lane-contiguous staging.
//  * Per-lane partial row-sums in-loop; single shfl_xor reduce after loop.
//  * kt+1 global prefetch issued before the second barrier.
//  * 1-D grid 576, XCD-aware swizzle (8 x 72, bijective).
// ---------------------------------------------------------------------------
__global__ __launch_bounds__(256, 2) void attn_k(
    const unsigned short* __restrict__ Y,    // [4][8][MATSZ] projections bf16
    const unsigned short* __restrict__ VT,   // [2][8][256][2304] bf16
    float* __restrict__ out)                 // [2][8][MATSZ] fp32
{
    // Ks 64x256 linear+xor (32768B) | Vs 256x64 linear+xor (32768B) | Ps 4x16x72 (9216B)
    __shared__ __align__(16) unsigned short lds[16384 + 16384 + 4608];  // 74752B
    unsigned short* Ks = lds;
    unsigned short* Vs = lds + 16384;
    unsigned short* Ps = lds + 32768;

    int bid = blockIdx.x;
    int wg = (bid & 7) * 72 + (bid >> 3);   // XCD swizzle (576 = 8*72, bijective)
    int qt = wg % 36;
    int ab = wg / 36;
    int a = ab >> 3, b = ab & 7;
    const unsigned short* Qp = Y + (size_t)(a * 8 + b) * MATSZ;        // q(l)/q(r)
    const unsigned short* Kp = Y + (size_t)((3 - a) * 8 + b) * MATSZ;  // k(r)/k(l)
    const unsigned short* Vp = VT + (size_t)((1 - a) * 8 + b) * MATSZ;
    float* Op = out + (size_t)ab * MATSZ;

    int t = threadIdx.x;
    int w = t >> 6, lane = t & 63;
    int l15 = lane & 15, quad = lane >> 4;

    // staging: flat byte f = k*4096 + t*16 within the 32KB tile.
    // K logical [key][c]: key = f>>9 = k*8 + (t>>5); phys = f ^ ((key&7)<<4)
    // V logical [c][key]: c   = f>>7 = k*32 + (t>>3); phys = f ^ ((c&7)<<4)
    const unsigned short* ksrc0 = Kp + t * 8;                          // + k*2048/iter
    const unsigned short* vsrc0 = Vp + (size_t)(t >> 3) * NTOK + ((t & 7) << 3);
    int kxor = ((t >> 5) & 7) << 4;      // (key&7)<<4  [R2 FIX: was &1]
    int vxor = ((t >> 3) & 7) << 4;      // (c&7)<<4,   constant per thread
    char* kdst = (char*)Ks + ((t * 16) ^ kxor);
    char* vdst = (char*)Vs + ((t * 16) ^ vxor);
    int rxor = (l15 & 7) << 4;           // read-side swizzle (row&7 == l15&7)

    bf16x8 qf[8];
    {
        const unsigned short* qp = Qp + (size_t)(qt * 64 + w * 16 + l15) * CH + quad * 8;
#pragma unroll
        for (int kc = 0; kc < 8; ++kc) qf[kc] = *(const bf16x8*)(qp + kc * 32);
    }
    f4v zero4 = {0.f, 0.f, 0.f, 0.f};
    f4v acc_o[16];
#pragma unroll
    for (int i = 0; i < 16; ++i) acc_o[i] = zero4;
    float l_acc[4] = {0.f, 0.f, 0.f, 0.f};
    __bf16* Pw = (__bf16*)(Ps + w * 16 * 72);

    // preload tile kt=0 into registers
    u32x4 kreg[8], vreg[8];
#pragma unroll
    for (int k = 0; k < 8; ++k) kreg[k] = *(const u32x4*)(ksrc0 + k * 2048);
#pragma unroll
    for (int k = 0; k < 8; ++k) vreg[k] = *(const u32x4*)(vsrc0 + (size_t)k * 32 * NTOK);

    for (int kt = 0; kt < 36; ++kt) {
        __syncthreads();     // previous iteration's LDS readers done
#pragma unroll
        for (int k = 0; k < 8; ++k) *(u32x4*)(kdst + k * 4096) = kreg[k];
#pragma unroll
        for (int k = 0; k < 8; ++k) *(u32x4*)(vdst + k * 4096) = vreg[k];

        if (kt < 35) {       // issue kt+1 prefetch before the barrier
            const unsigned short* kn = ksrc0 + (size_t)(kt + 1) * 16384;
            const unsigned short* vn = vsrc0 + (size_t)(kt + 1) * 64;
#pragma unroll
            for (int k = 0; k < 8; ++k) kreg[k] = *(const u32x4*)(kn + k * 2048);
#pragma unroll
            for (int k = 0; k < 8; ++k) vreg[k] = *(const u32x4*)(vn + (size_t)k * 32 * NTOK);
        }
        __syncthreads();     // staged tile visible

        // S = Q K^T  (wave: 16 q-rows x 64 keys); kf read with XOR swizzle
        f4v accs[4] = {zero4, zero4, zero4, zero4};
#pragma unroll
        for (int kc = 0; kc < 8; ++kc) {
#pragma unroll
            for (int ct = 0; ct < 4; ++ct) {
                const char* kaddr = (const char*)Ks + ((ct * 16 + l15) << 9)
                                  + (((kc << 6) + (quad << 4)) ^ rxor);
                bf16x8 kf = *(const bf16x8*)kaddr;
                accs[ct] = __builtin_amdgcn_mfma_f32_16x16x32_bf16(qf[kc], kf, accs[ct], 0, 0, 0);
            }
        }
        // P = exp(S/256); per-lane PARTIAL row sums (cross-lane reduce deferred)
        float pv[4][4];
#pragma unroll
        for (int r = 0; r < 4; ++r) {
#pragma unroll
            for (int ct = 0; ct < 4; ++ct) {
                float pe = __expf(accs[ct][r] * (1.0f / 256.0f));
                pv[ct][r] = pe;
                l_acc[r] += pe;
            }
        }
        // P: C-layout -> per-wave LDS region -> A-layout (wave-local fence)
#pragma unroll
        for (int r = 0; r < 4; ++r)
#pragma unroll
            for (int ct = 0; ct < 4; ++ct)
                Pw[(quad * 4 + r) * 72 + ct * 16 + l15] = (__bf16)pv[ct][r];
        __asm__ volatile("s_waitcnt lgkmcnt(0)" ::: "memory");
        // O += P @ V  (vf read with XOR swizzle)
#pragma unroll
        for (int kc = 0; kc < 2; ++kc) {
            bf16x8 pf = *(const bf16x8*)(Pw + l15 * 72 + kc * 32 + quad * 8);
#pragma unroll
            for (int ct = 0; ct < 16; ++ct) {
                const char* vaddr = (const char*)Vs + ((ct * 16 + l15) << 7)
                                  + (((kc << 6) + (quad << 4)) ^ rxor);
                bf16x8 vf = *(const bf16x8*)vaddr;
                acc_o[ct] = __builtin_amdgcn_mfma_f32_16x16x32_bf16(pf, vf, acc_o[ct], 0, 0, 0);
            }
        }
    }

    // deferred row-sum: reduce per-lane partials across the 16-lane group
#pragma unroll
    for (int r = 0; r < 4; ++r) {
        float rs = l_acc[r];
        rs += __shfl_xor(rs, 1, 64);
        rs += __shfl_xor(rs, 2, 64);
        rs += __shfl_xor(rs, 4, 64);
        rs += __shfl_xor(rs, 8, 64);
        l_acc[r] = rs;
    }

    // epilogue: normalize, fp32 transpose through LDS, coalesced stores
    __syncthreads();
    float* Ot = (float*)lds;   // [256][73] fp32 = 74752B, exactly fits
#pragma unroll
    for (int ct = 0; ct < 16; ++ct)
#pragma unroll
        for (int r = 0; r < 4; ++r) {
            float val = acc_o[ct][r] / l_acc[r];
            Ot[(ct * 16 + l15) * 73 + (w * 16 + quad * 4 + r)] = val;
        }
    __syncthreads();
    for (int cg = 0; cg < 64; ++cg) {
        int c = cg * 4 + w;
        Op[(size_t)c * NTOK + qt * 64 + lane] = Ot[c * 73 + lane];
    }
}

// ---------------------------------------------------------------------------
extern "C" void kernel_launch(void* const* d_in, const int* in_sizes, int n_in,
                              void* d_out, int out_size, void* d_ws, size_t ws_size,
                              hipStream_t stream) {
    (void)in_sizes; (void)n_in; (void)out_size; (void)ws_size;
    const float* feaL  = (const float*)d_in[0];
    const float* feaR  = (const float*)d_in[1];
    const float* Wq    = (const float*)d_in[2];
    const float* bq    = (const float*)d_in[3];
    const float* gq    = (const float*)d_in[4];
    const float* betaq = (const float*)d_in[5];
    const float* mq    = (const float*)d_in[6];
    const float* vq    = (const float*)d_in[7];
    const float* Wk    = (const float*)d_in[8];
    const float* bk    = (const float*)d_in[9];
    const float* gk    = (const float*)d_in[10];
    const float* betak = (const float*)d_in[11];
    const float* mk    = (const float*)d_in[12];
    const float* vk    = (const float*)d_in[13];

    // workspace (bf16): XT/VT alias 16*MATSZ (18.9MB) | Y 32*MATSZ (37.7MB)
    unsigned short* XT = (unsigned short*)d_ws;   // reused as VT after proj
    unsigned short* VT = XT;
    unsigned short* Yb = XT + (size_t)16 * MATSZ;
    float* out = (float*)d_out;   // fp32: reference output dtype

    dim3 blk(256);
    // XT[s][b][pos][c] = fea[b][c][pos]
    tpose_k<<<dim3(144, 16), blk, 0, stream>>>(feaL, feaR, XT, 256, 2304);
    proj_k<<<dim3(144, 32), blk, 0, stream>>>(XT, Wq, Wk, bq, bk, gq, gk,
                                              betaq, betak, mq, mk, vq, vk, Yb);
    // VT[s][b][c][n] = fea_flat[n*256+c]
    tpose_k<<<dim3(144, 16), blk, 0, stream>>>(feaL, feaR, VT, 2304, 256);
    attn_k<<<dim3(576), blk, 0, stream>>>(Yb, VT, out);
}